// Round 12
// baseline (87.299 us; speedup 1.0000x reference)
//
#include <hip/hip_runtime.h>

// ---------------------------------------------------------------------------
// Net_65798898975283: 2x GraphConv (add-aggr) + 3-layer MLP head + log_softmax
// N=20000 nodes, E=320000 edges, dims 256->128->64->128->64->10
//
// R11 (5 dispatches): R10 structure + deeper gather ILP (8 outstanding row
// loads/lane) + gather2_mlp at 16 nodes/block (grid 1250, 2x gather TLP).
//   1 memset        cnt[N] = 0
//   2 prep          WT swz + x->bf16 swz + edge bucket scatter
//   3 gemm1_swz     C1A = [x@W1_rel | x@W1_root+b1]   (1252 blocks)
//   4 gather1_gemm2 16 nodes/block: gather H1 -> LDS -> dual GEMM -> C2A
//   5 gather2_mlp   16 nodes/block: gather H2 -> LDS -> mlp1 -> mlp2 -> head
// ---------------------------------------------------------------------------

#define NNODES 20000
#define NEDGES 320000
#define CAP 64          // bucket capacity per node

typedef __attribute__((ext_vector_type(8))) short bf16x8;
typedef __attribute__((ext_vector_type(4))) float f32x4;

__device__ inline short f2bf(float f) {
    unsigned u = __builtin_bit_cast(unsigned, f);
    u += 0x7FFFu + ((u >> 16) & 1u);   // RNE (finite inputs)
    return (short)(u >> 16);
}
__device__ inline float bf2f(short h) {
    unsigned u = ((unsigned)(unsigned short)h) << 16;
    return __builtin_bit_cast(float, u);
}

// swizzled offset for element (n, k) of an [N][K] matrix, ktiles = K/32:
// chunk = (n>>4)*ktiles + (k>>5); lane = ((k>>3)&3)*16 + (n&15), elem k&7
__device__ inline size_t swz_off(int n, int k, int ktiles) {
    return (size_t)((n >> 4) * ktiles + (k >> 5)) * 512 +
           ((((k >> 3) & 3) * 16 + (n & 15)) << 3) + (k & 7);
}

// ---------------- prep: WT swizzle + x->bf16 swizzle + edge buckets ---------
// blocks [0,384): WT; [384, 2884): x cvt; [2884, 2884+1250): edge scatter
__global__ void prep_kernel(const float* __restrict__ W1r, const float* __restrict__ W1o,
                            const float* __restrict__ W2r, const float* __restrict__ W2o,
                            const float* __restrict__ L1,  const float* __restrict__ L2,
                            short* __restrict__ WT,
                            const float* __restrict__ x, short* __restrict__ XBs,
                            const int* __restrict__ src, const int* __restrict__ dst,
                            int* __restrict__ cnt, int* __restrict__ nbr) {
    const int b = blockIdx.x;
    if (b < 384) {
        int idx = b * 256 + threadIdx.x;   // 0..98303
        if (idx < 65536) {                       // WT1s: [256 n][256 k], swizzled
            int n = idx >> 8, k = idx & 255;
            float v = (n < 128) ? W1r[k * 128 + n] : W1o[k * 128 + (n - 128)];
            WT[swz_off(n, k, 8)] = f2bf(v);
        } else if (idx < 65536 + 16384) {        // WT2s: [128][128], swizzled
            int i = idx - 65536;
            int n = i >> 7, k = i & 127;
            float v = (n < 64) ? W2r[k * 64 + n] : W2o[k * 64 + (n - 64)];
            WT[65536 + swz_off(n, k, 4)] = f2bf(v);
        } else if (idx < 65536 + 16384 + 8192) { // WT3 [128][64] row-major
            int i = idx - (65536 + 16384);
            int n = i >> 6, k = i & 63;
            WT[idx] = f2bf(L1[k * 128 + n]);
        } else {                                 // WT4 [64][128] row-major
            int i = idx - (65536 + 16384 + 8192);
            int n = i >> 7, k = i & 127;
            WT[idx] = f2bf(L2[k * 64 + n]);
        }
    } else if (b < 384 + 2500) {
        // x -> bf16 swizzled chunks: thread t handles row t>>5, cols (t&31)*8..+7
        int t = (b - 384) * 256 + threadIdx.x;   // 0..639999
        int row = t >> 5, q = t & 31;
        const float* xp = x + (size_t)row * 256 + q * 8;
        float4 f0 = *reinterpret_cast<const float4*>(xp);
        float4 f1 = *reinterpret_cast<const float4*>(xp + 4);
        bf16x8 o;
        o[0] = f2bf(f0.x); o[1] = f2bf(f0.y); o[2] = f2bf(f0.z); o[3] = f2bf(f0.w);
        o[4] = f2bf(f1.x); o[5] = f2bf(f1.y); o[6] = f2bf(f1.z); o[7] = f2bf(f1.w);
        size_t off = (size_t)((row >> 4) * 8 + (q >> 2)) * 512 +
                     (((q & 3) * 16 + (row & 15)) << 3);
        *reinterpret_cast<bf16x8*>(XBs + off) = o;
    } else {
        int e = (b - 384 - 2500) * 256 + threadIdx.x;   // exactly covers NEDGES
        int d = dst[e];
        int p = atomicAdd(&cnt[d], 1);
        if (p < CAP) nbr[(d << 6) + p] = src[e];
    }
}

// ---------------- gemm1: C1A[M][256] = [XB@W1_rel | XB@W1_root+b1] ----------
// Swizzled operands; block = 4 waves x (16 rows x 64 cols); grid = 313*4.
__global__ __launch_bounds__(256)
void gemm1_swz(const short* __restrict__ XBs, const short* __restrict__ WT1s,
               const float* __restrict__ b1, short* __restrict__ C1A, int M) {
    const int tid = threadIdx.x;
    const int cb = blockIdx.x & 3;
    const int rb = blockIdx.x >> 2;
    const int wid = tid >> 6, lane = tid & 63;
    const int lr = lane & 15, lg = lane >> 4;
    const int rt = rb * 4 + wid;                 // 16-row tile (padded region ok)
    const short* abase = XBs + (size_t)rt * 4096 + lane * 8;
    const short* bbase = WT1s + (size_t)(cb * 4) * 4096 + lane * 8;
    f32x4 acc[4] = {};
    #pragma unroll
    for (int ks = 0; ks < 8; ++ks) {
        bf16x8 a = *reinterpret_cast<const bf16x8*>(abase + ks * 512);
        #pragma unroll
        for (int nt = 0; nt < 4; ++nt) {
            bf16x8 bb = *reinterpret_cast<const bf16x8*>(bbase + (nt * 8 + ks) * 512);
            acc[nt] = __builtin_amdgcn_mfma_f32_16x16x32_bf16(a, bb, acc[nt], 0, 0, 0);
        }
    }
    #pragma unroll
    for (int r = 0; r < 4; ++r) {
        int row = rt * 16 + lg * 4 + r;
        if (row >= M) continue;
        #pragma unroll
        for (int nt = 0; nt < 4; ++nt) {
            int col = cb * 64 + nt * 16 + lr;
            float v = acc[nt][r];
            if (col >= 128) v += b1[col - 128];
            C1A[(size_t)row * 256 + col] = f2bf(v);
        }
    }
}

// ---------------- gather1 + gemm2 fused -------------------------------------
// Block = 16 nodes. Phase A: 16 lanes/node, 8-deep ILP gather
//   H1[r,:] = relu(C1A[node,128:] + sum C1A[nbr,0:128]) into LDS.
// Phase B: 4 waves x (16 rows x 32 cols) dual GEMM vs swizzled WT2s.
__global__ __launch_bounds__(256)
void gather1_gemm2(const short* __restrict__ C1A,
                   const int* __restrict__ cnt, const int* __restrict__ nbr,
                   const short* __restrict__ WT2s, const float* __restrict__ b2,
                   short* __restrict__ C2A) {
    __shared__ short H1s[16][136];
    const int tid = threadIdx.x;
    const int bm = blockIdx.x * 16;

    {   // gather phase
        const int node = bm + (tid >> 4);
        const int c8 = (tid & 15) * 8;
        float acc[8];
        bf16x8 iv = *reinterpret_cast<const bf16x8*>(C1A + (size_t)node * 256 + 128 + c8);
        #pragma unroll
        for (int i = 0; i < 8; ++i) acc[i] = bf2f(iv[i]);
        const int beg = node << 6;
        const int end = beg + min(cnt[node], CAP);
        int j = beg;
        for (; j + 7 < end; j += 8) {
            int s[8];
            #pragma unroll
            for (int q = 0; q < 8; ++q) s[q] = nbr[j + q];
            bf16x8 v[8];
            #pragma unroll
            for (int q = 0; q < 8; ++q)
                v[q] = *reinterpret_cast<const bf16x8*>(C1A + (size_t)s[q] * 256 + c8);
            #pragma unroll
            for (int q = 0; q < 8; ++q)
                #pragma unroll
                for (int i = 0; i < 8; ++i) acc[i] += bf2f(v[q][i]);
        }
        for (; j < end; ++j) {
            int sx = nbr[j];
            bf16x8 vv = *reinterpret_cast<const bf16x8*>(C1A + (size_t)sx * 256 + c8);
            #pragma unroll
            for (int i = 0; i < 8; ++i) acc[i] += bf2f(vv[i]);
        }
        bf16x8 o;
        #pragma unroll
        for (int i = 0; i < 8; ++i) o[i] = f2bf(fmaxf(acc[i], 0.f));
        *reinterpret_cast<bf16x8*>(&H1s[tid >> 4][c8]) = o;
    }
    __syncthreads();

    // gemm phase: wave w -> cols [w*32, w*32+32)
    const int w = tid >> 6, lane = tid & 63;
    const int lr = lane & 15, lg = lane >> 4;
    f32x4 acc[2] = {};
    #pragma unroll
    for (int ks = 0; ks < 4; ++ks) {
        bf16x8 a = *reinterpret_cast<const bf16x8*>(&H1s[lr][lg * 8 + ks * 32]);
        #pragma unroll
        for (int nt = 0; nt < 2; ++nt) {
            int ntg = w * 2 + nt;   // global 16-col tile index
            bf16x8 bb = *reinterpret_cast<const bf16x8*>(
                WT2s + (size_t)(ntg * 4 + ks) * 512 + lane * 8);
            acc[nt] = __builtin_amdgcn_mfma_f32_16x16x32_bf16(a, bb, acc[nt], 0, 0, 0);
        }
    }
    #pragma unroll
    for (int r = 0; r < 4; ++r) {
        int row = bm + lg * 4 + r;
        #pragma unroll
        for (int nt = 0; nt < 2; ++nt) {
            int col = w * 32 + nt * 16 + lr;
            float v = acc[nt][r];
            if (col >= 64) v += b2[col - 64];
            C2A[(size_t)row * 128 + col] = f2bf(v);
        }
    }
}

// ---------------- gather2 + mlp + head fused (16 nodes/block) ---------------
// Phase A: 16 lanes/node (8B loads), 8-deep ILP gather H2 (no relu) into LDS.
// mlp1: wave w -> 16 rows x cols [w*32,w*32+32); mlp2: wave w -> cols
// [w*16,w*16+16); head: threads 0..15.
__global__ __launch_bounds__(256)
void gather2_mlp(const short* __restrict__ C2A,
                 const int* __restrict__ cnt, const int* __restrict__ nbr,
                 const short* __restrict__ WT3, const float* __restrict__ b3,
                 const short* __restrict__ WT4, const float* __restrict__ b4,
                 const float* __restrict__ W5, const float* __restrict__ b5,
                 float* __restrict__ out) {
    __shared__ short H2s[16][72];
    __shared__ short H3s[16][136];
    __shared__ short WU[9216];           // WT3 as [128][72], then WT4 as [64][136]
    __shared__ short H4s[16][72];
    __shared__ float cb[842];            // b3[128] b4[64] W5[640] b5[10]
    const int tid = threadIdx.x;
    const int bm = blockIdx.x * 16;
    const int w = tid >> 6, lane = tid & 63;
    const int lr = lane & 15, lg = lane >> 4;

    for (int i = tid; i < 842; i += 256) {
        float v;
        if (i < 128) v = b3[i];
        else if (i < 192) v = b4[i - 128];
        else if (i < 832) v = W5[i - 192];
        else v = b5[i - 832];
        cb[i] = v;
    }
    #pragma unroll
    for (int p = 0; p < 4; ++p) {
        int L = tid + p * 256;           // 0..1023  (WT3 [128][64])
        int n = L >> 3;
        int kc = (L & 7) * 8;
        *reinterpret_cast<bf16x8*>(&WU[n * 72 + kc]) =
            *reinterpret_cast<const bf16x8*>(WT3 + (size_t)n * 64 + kc);
    }

    {   // gather phase: node = bm + tid/16, 16 lanes x 4 shorts (8B)
        const int node = bm + (tid >> 4);
        const int c4 = (tid & 15) * 4;
        float acc[4];
        short4 iv = *reinterpret_cast<const short4*>(C2A + (size_t)node * 128 + 64 + c4);
        acc[0] = bf2f(iv.x); acc[1] = bf2f(iv.y); acc[2] = bf2f(iv.z); acc[3] = bf2f(iv.w);
        const int beg = node << 6;
        const int end = beg + min(cnt[node], CAP);
        int j = beg;
        for (; j + 7 < end; j += 8) {
            int s[8];
            #pragma unroll
            for (int q = 0; q < 8; ++q) s[q] = nbr[j + q];
            short4 v[8];
            #pragma unroll
            for (int q = 0; q < 8; ++q)
                v[q] = *reinterpret_cast<const short4*>(C2A + (size_t)s[q] * 128 + c4);
            #pragma unroll
            for (int q = 0; q < 8; ++q) {
                acc[0] += bf2f(v[q].x); acc[1] += bf2f(v[q].y);
                acc[2] += bf2f(v[q].z); acc[3] += bf2f(v[q].w);
            }
        }
        for (; j < end; ++j) {
            int sx = nbr[j];
            short4 vv = *reinterpret_cast<const short4*>(C2A + (size_t)sx * 128 + c4);
            acc[0] += bf2f(vv.x); acc[1] += bf2f(vv.y);
            acc[2] += bf2f(vv.z); acc[3] += bf2f(vv.w);
        }
        short4 o;
        o.x = f2bf(acc[0]); o.y = f2bf(acc[1]); o.z = f2bf(acc[2]); o.w = f2bf(acc[3]);
        *reinterpret_cast<short4*>(&H2s[tid >> 4][c4]) = o;
    }
    __syncthreads();

    // mlp1: H3 = relu(H2 @ WT3^T + b3), 16x128, K=64; wave w -> cols w*32..
    {
        f32x4 a1[2] = {};
        #pragma unroll
        for (int ks = 0; ks < 2; ++ks) {
            bf16x8 a = *reinterpret_cast<const bf16x8*>(&H2s[lr][ks * 32 + lg * 8]);
            #pragma unroll
            for (int nt = 0; nt < 2; ++nt) {
                bf16x8 b = *reinterpret_cast<const bf16x8*>(
                    &WU[(w * 32 + nt * 16 + lr) * 72 + ks * 32 + lg * 8]);
                a1[nt] = __builtin_amdgcn_mfma_f32_16x16x32_bf16(a, b, a1[nt], 0, 0, 0);
            }
        }
        #pragma unroll
        for (int r = 0; r < 4; ++r) {
            int row = lg * 4 + r;
            #pragma unroll
            for (int nt = 0; nt < 2; ++nt) {
                int col = w * 32 + nt * 16 + lr;
                H3s[row][col] = f2bf(fmaxf(a1[nt][r] + cb[col], 0.f));
            }
        }
    }
    __syncthreads();

    #pragma unroll
    for (int p = 0; p < 4; ++p) {
        int L = tid + p * 256;           // WT4 [64][128] -> WU stride 136
        int n = L >> 4;
        int kc = (L & 15) * 8;
        *reinterpret_cast<bf16x8*>(&WU[n * 136 + kc]) =
            *reinterpret_cast<const bf16x8*>(WT4 + (size_t)n * 128 + kc);
    }
    __syncthreads();

    // mlp2: H4 = relu(H3 @ WT4^T + b4), 16x64, K=128; wave w -> cols w*16..
    {
        f32x4 a2 = {};
        #pragma unroll
        for (int ks = 0; ks < 4; ++ks) {
            bf16x8 a = *reinterpret_cast<const bf16x8*>(&H3s[lr][ks * 32 + lg * 8]);
            bf16x8 b = *reinterpret_cast<const bf16x8*>(
                &WU[(w * 16 + lr) * 136 + ks * 32 + lg * 8]);
            a2 = __builtin_amdgcn_mfma_f32_16x16x32_bf16(a, b, a2, 0, 0, 0);
        }
        #pragma unroll
        for (int r = 0; r < 4; ++r) {
            int row = lg * 4 + r;
            int col = w * 16 + lr;
            H4s[row][col] = f2bf(fmaxf(a2[r] + cb[128 + col], 0.f));
        }
    }
    __syncthreads();

    // head: log_softmax(H4 @ W5 + b5), threads 0..15
    if (tid < 16) {
        int node = bm + tid;
        float logit[10];
        #pragma unroll
        for (int c = 0; c < 10; ++c) logit[c] = cb[832 + c];
        #pragma unroll
        for (int k = 0; k < 64; ++k) {
            float hv = bf2f(H4s[tid][k]);
            #pragma unroll
            for (int c = 0; c < 10; ++c) logit[c] += hv * cb[192 + k * 10 + c];
        }
        float m = logit[0];
        #pragma unroll
        for (int c = 1; c < 10; ++c) m = fmaxf(m, logit[c]);
        float s = 0.f;
        #pragma unroll
        for (int c = 0; c < 10; ++c) s += expf(logit[c] - m);
        float lse = m + logf(s);
        float* o = out + (size_t)node * 10;
        #pragma unroll
        for (int c = 0; c < 10; ++c) o[c] = logit[c] - lse;
    }
}

extern "C" void kernel_launch(void* const* d_in, const int* in_sizes, int n_in,
                              void* d_out, int out_size, void* d_ws, size_t ws_size,
                              hipStream_t stream) {
    const float* x       = (const float*)d_in[0];
    const int*   edge    = (const int*)d_in[1];
    const int*   src     = edge;            // edge_index[0]
    const int*   dst     = edge + NEDGES;   // edge_index[1]
    const float* W1_rel  = (const float*)d_in[2];
    const float* W1_root = (const float*)d_in[3];
    const float* b1      = (const float*)d_in[4];
    const float* W2_rel  = (const float*)d_in[5];
    const float* W2_root = (const float*)d_in[6];
    const float* b2      = (const float*)d_in[7];
    const float* lin1_w  = (const float*)d_in[8];
    const float* lin1_b  = (const float*)d_in[9];
    const float* lin2_w  = (const float*)d_in[10];
    const float* lin2_b  = (const float*)d_in[11];
    const float* lin3_w  = (const float*)d_in[12];
    const float* lin3_b  = (const float*)d_in[13];
    float* out = (float*)d_out;

    const int M = NNODES;
    char* p = (char*)d_ws;
    auto alloc = [&](size_t bytes) { char* r = p; p += (bytes + 63) & ~63ull; return r; };
    short* WT   = (short*)alloc(98304 * 2);
    short* WT1s = WT;                 // swizzled [256][256]
    short* WT2s = WT1s + 65536;       // swizzled [128][128]
    short* WT3  = WT2s + 16384;       // [128][64] row-major
    short* WT4  = WT3 + 8192;         // [64][128] row-major
    short* XBs  = (short*)alloc((size_t)1252 * 4096 * 2);  // x bf16, chunk layout (padded)
    short* C1A  = (short*)alloc((size_t)M * 256 * 2);      // row-major
    short* C2A  = (short*)alloc((size_t)M * 128 * 2);      // row-major
    int* cnt = (int*)alloc(NNODES * 4);
    int* nbr = (int*)alloc((size_t)NNODES * CAP * 4);      // buckets

    hipMemsetAsync(cnt, 0, NNODES * sizeof(int), stream);
    prep_kernel<<<384 + 2500 + NEDGES / 256, 256, 0, stream>>>(
        W1_rel, W1_root, W2_rel, W2_root, lin1_w, lin2_w, WT, x, XBs,
        src, dst, cnt, nbr);

    gemm1_swz<<<4 * 313, 256, 0, stream>>>(XBs, WT1s, b1, C1A, M);
    gather1_gemm2<<<NNODES / 16, 256, 0, stream>>>(C1A, cnt, nbr, WT2s, b2, C2A);
    gather2_mlp<<<NNODES / 16, 256, 0, stream>>>(C2A, cnt, nbr, WT3, lin1_b,
                                                 WT4, lin2_b, lin3_w, lin3_b, out);
}

// Round 13
// 81.305 us; speedup vs baseline: 1.0737x; 1.0737x over previous
//
#include <hip/hip_runtime.h>

// ---------------------------------------------------------------------------
// Net_65798898975283: 2x GraphConv (add-aggr) + 3-layer MLP head + log_softmax
// N=20000 nodes, E=320000 edges, dims 256->128->64->128->64->10
//
// R12 = exact revert to R10 (78.1us best). R11's two changes both regressed:
// 8-deep gather ILP (VGPR pressure, delayed accumulation) and g2m at 16
// nodes/block (doubled per-block weight-staging overhead, half-idle MFMAs).
// Lesson: when fusing compute onto a gather grid, bigger blocks amortize
// fixed costs; 16-node g1g2 / 32-node g2m is the measured sweet spot.
//
//   1 memset        cnt[N] = 0
//   2 prep          WT swz + x->bf16 swz + edge bucket scatter
//   3 gemm1_swz     C1A = [x@W1_rel | x@W1_root+b1]   (1252 blocks)
//   4 gather1_gemm2 16 nodes/block: gather H1 -> LDS -> dual GEMM -> C2A
//   5 gather2_mlp   32 nodes/block: gather H2 -> LDS -> mlp1 -> mlp2 -> head
// ---------------------------------------------------------------------------

#define NNODES 20000
#define NEDGES 320000
#define CAP 64          // bucket capacity per node

typedef __attribute__((ext_vector_type(8))) short bf16x8;
typedef __attribute__((ext_vector_type(4))) float f32x4;

__device__ inline short f2bf(float f) {
    unsigned u = __builtin_bit_cast(unsigned, f);
    u += 0x7FFFu + ((u >> 16) & 1u);   // RNE (finite inputs)
    return (short)(u >> 16);
}
__device__ inline float bf2f(short h) {
    unsigned u = ((unsigned)(unsigned short)h) << 16;
    return __builtin_bit_cast(float, u);
}

// swizzled offset for element (n, k) of an [N][K] matrix, ktiles = K/32:
// chunk = (n>>4)*ktiles + (k>>5); lane = ((k>>3)&3)*16 + (n&15), elem k&7
__device__ inline size_t swz_off(int n, int k, int ktiles) {
    return (size_t)((n >> 4) * ktiles + (k >> 5)) * 512 +
           ((((k >> 3) & 3) * 16 + (n & 15)) << 3) + (k & 7);
}

// ---------------- prep: WT swizzle + x->bf16 swizzle + edge buckets ---------
// blocks [0,384): WT; [384, 2884): x cvt; [2884, 2884+1250): edge scatter
__global__ void prep_kernel(const float* __restrict__ W1r, const float* __restrict__ W1o,
                            const float* __restrict__ W2r, const float* __restrict__ W2o,
                            const float* __restrict__ L1,  const float* __restrict__ L2,
                            short* __restrict__ WT,
                            const float* __restrict__ x, short* __restrict__ XBs,
                            const int* __restrict__ src, const int* __restrict__ dst,
                            int* __restrict__ cnt, int* __restrict__ nbr) {
    const int b = blockIdx.x;
    if (b < 384) {
        int idx = b * 256 + threadIdx.x;   // 0..98303
        if (idx < 65536) {                       // WT1s: [256 n][256 k], swizzled
            int n = idx >> 8, k = idx & 255;
            float v = (n < 128) ? W1r[k * 128 + n] : W1o[k * 128 + (n - 128)];
            WT[swz_off(n, k, 8)] = f2bf(v);
        } else if (idx < 65536 + 16384) {        // WT2s: [128][128], swizzled
            int i = idx - 65536;
            int n = i >> 7, k = i & 127;
            float v = (n < 64) ? W2r[k * 64 + n] : W2o[k * 64 + (n - 64)];
            WT[65536 + swz_off(n, k, 4)] = f2bf(v);
        } else if (idx < 65536 + 16384 + 8192) { // WT3 [128][64] row-major
            int i = idx - (65536 + 16384);
            int n = i >> 6, k = i & 63;
            WT[idx] = f2bf(L1[k * 128 + n]);
        } else {                                 // WT4 [64][128] row-major
            int i = idx - (65536 + 16384 + 8192);
            int n = i >> 7, k = i & 127;
            WT[idx] = f2bf(L2[k * 64 + n]);
        }
    } else if (b < 384 + 2500) {
        // x -> bf16 swizzled chunks: thread t handles row t>>5, cols (t&31)*8..+7
        int t = (b - 384) * 256 + threadIdx.x;   // 0..639999
        int row = t >> 5, q = t & 31;
        const float* xp = x + (size_t)row * 256 + q * 8;
        float4 f0 = *reinterpret_cast<const float4*>(xp);
        float4 f1 = *reinterpret_cast<const float4*>(xp + 4);
        bf16x8 o;
        o[0] = f2bf(f0.x); o[1] = f2bf(f0.y); o[2] = f2bf(f0.z); o[3] = f2bf(f0.w);
        o[4] = f2bf(f1.x); o[5] = f2bf(f1.y); o[6] = f2bf(f1.z); o[7] = f2bf(f1.w);
        size_t off = (size_t)((row >> 4) * 8 + (q >> 2)) * 512 +
                     (((q & 3) * 16 + (row & 15)) << 3);
        *reinterpret_cast<bf16x8*>(XBs + off) = o;
    } else {
        int e = (b - 384 - 2500) * 256 + threadIdx.x;   // exactly covers NEDGES
        int d = dst[e];
        int p = atomicAdd(&cnt[d], 1);
        if (p < CAP) nbr[(d << 6) + p] = src[e];
    }
}

// ---------------- gemm1: C1A[M][256] = [XB@W1_rel | XB@W1_root+b1] ----------
// Swizzled operands; block = 4 waves x (16 rows x 64 cols); grid = 313*4.
__global__ __launch_bounds__(256)
void gemm1_swz(const short* __restrict__ XBs, const short* __restrict__ WT1s,
               const float* __restrict__ b1, short* __restrict__ C1A, int M) {
    const int tid = threadIdx.x;
    const int cb = blockIdx.x & 3;
    const int rb = blockIdx.x >> 2;
    const int wid = tid >> 6, lane = tid & 63;
    const int lr = lane & 15, lg = lane >> 4;
    const int rt = rb * 4 + wid;                 // 16-row tile (padded region ok)
    const short* abase = XBs + (size_t)rt * 4096 + lane * 8;
    const short* bbase = WT1s + (size_t)(cb * 4) * 4096 + lane * 8;
    f32x4 acc[4] = {};
    #pragma unroll
    for (int ks = 0; ks < 8; ++ks) {
        bf16x8 a = *reinterpret_cast<const bf16x8*>(abase + ks * 512);
        #pragma unroll
        for (int nt = 0; nt < 4; ++nt) {
            bf16x8 bb = *reinterpret_cast<const bf16x8*>(bbase + (nt * 8 + ks) * 512);
            acc[nt] = __builtin_amdgcn_mfma_f32_16x16x32_bf16(a, bb, acc[nt], 0, 0, 0);
        }
    }
    #pragma unroll
    for (int r = 0; r < 4; ++r) {
        int row = rt * 16 + lg * 4 + r;
        if (row >= M) continue;
        #pragma unroll
        for (int nt = 0; nt < 4; ++nt) {
            int col = cb * 64 + nt * 16 + lr;
            float v = acc[nt][r];
            if (col >= 128) v += b1[col - 128];
            C1A[(size_t)row * 256 + col] = f2bf(v);
        }
    }
}

// ---------------- gather1 + gemm2 fused -------------------------------------
// Block = 16 nodes. Phase A: 16 lanes/node gather
//   H1[r,:] = relu(C1A[node,128:] + sum C1A[nbr,0:128]) into LDS.
// Phase B: 4 waves x (16 rows x 32 cols) dual GEMM vs swizzled WT2s:
//   C2A[node][0:64] = H1@W2_rel, C2A[node][64:128] = H1@W2_root + b2.
__global__ __launch_bounds__(256)
void gather1_gemm2(const short* __restrict__ C1A,
                   const int* __restrict__ cnt, const int* __restrict__ nbr,
                   const short* __restrict__ WT2s, const float* __restrict__ b2,
                   short* __restrict__ C2A) {
    __shared__ short H1s[16][136];
    const int tid = threadIdx.x;
    const int bm = blockIdx.x * 16;

    {   // gather phase
        const int node = bm + (tid >> 4);
        const int c8 = (tid & 15) * 8;
        float acc[8];
        bf16x8 iv = *reinterpret_cast<const bf16x8*>(C1A + (size_t)node * 256 + 128 + c8);
        #pragma unroll
        for (int i = 0; i < 8; ++i) acc[i] = bf2f(iv[i]);
        const int beg = node << 6;
        const int end = beg + min(cnt[node], CAP);
        int j = beg;
        for (; j + 3 < end; j += 4) {
            int s0 = nbr[j], s1 = nbr[j + 1], s2 = nbr[j + 2], s3 = nbr[j + 3];
            bf16x8 v0 = *reinterpret_cast<const bf16x8*>(C1A + (size_t)s0 * 256 + c8);
            bf16x8 v1 = *reinterpret_cast<const bf16x8*>(C1A + (size_t)s1 * 256 + c8);
            bf16x8 v2 = *reinterpret_cast<const bf16x8*>(C1A + (size_t)s2 * 256 + c8);
            bf16x8 v3 = *reinterpret_cast<const bf16x8*>(C1A + (size_t)s3 * 256 + c8);
            #pragma unroll
            for (int i = 0; i < 8; ++i)
                acc[i] += (bf2f(v0[i]) + bf2f(v1[i])) + (bf2f(v2[i]) + bf2f(v3[i]));
        }
        for (; j < end; ++j) {
            int s = nbr[j];
            bf16x8 vv = *reinterpret_cast<const bf16x8*>(C1A + (size_t)s * 256 + c8);
            #pragma unroll
            for (int i = 0; i < 8; ++i) acc[i] += bf2f(vv[i]);
        }
        bf16x8 o;
        #pragma unroll
        for (int i = 0; i < 8; ++i) o[i] = f2bf(fmaxf(acc[i], 0.f));
        *reinterpret_cast<bf16x8*>(&H1s[tid >> 4][c8]) = o;
    }
    __syncthreads();

    // gemm phase: wave w -> cols [w*32, w*32+32)
    const int w = tid >> 6, lane = tid & 63;
    const int lr = lane & 15, lg = lane >> 4;
    f32x4 acc[2] = {};
    #pragma unroll
    for (int ks = 0; ks < 4; ++ks) {
        bf16x8 a = *reinterpret_cast<const bf16x8*>(&H1s[lr][lg * 8 + ks * 32]);
        #pragma unroll
        for (int nt = 0; nt < 2; ++nt) {
            int ntg = w * 2 + nt;   // global 16-col tile index
            bf16x8 bb = *reinterpret_cast<const bf16x8*>(
                WT2s + (size_t)(ntg * 4 + ks) * 512 + lane * 8);
            acc[nt] = __builtin_amdgcn_mfma_f32_16x16x32_bf16(a, bb, acc[nt], 0, 0, 0);
        }
    }
    #pragma unroll
    for (int r = 0; r < 4; ++r) {
        int row = bm + lg * 4 + r;
        #pragma unroll
        for (int nt = 0; nt < 2; ++nt) {
            int col = w * 32 + nt * 16 + lr;
            float v = acc[nt][r];
            if (col >= 64) v += b2[col - 64];
            C2A[(size_t)row * 128 + col] = f2bf(v);
        }
    }
}

// ---------------- gather2 + mlp + head fused --------------------------------
// Block = 32 nodes. Phase A: 8 lanes/node gather H2 (no relu) into LDS.
// mlp1: wave w -> rows (w>>1)*16, cols (w&1)*64; mlp2: rows (w>>1)*16,
// cols (w&1)*32; head: threads 0..31.
__global__ __launch_bounds__(256)
void gather2_mlp(const short* __restrict__ C2A,
                 const int* __restrict__ cnt, const int* __restrict__ nbr,
                 const short* __restrict__ WT3, const float* __restrict__ b3,
                 const short* __restrict__ WT4, const float* __restrict__ b4,
                 const float* __restrict__ W5, const float* __restrict__ b5,
                 float* __restrict__ out) {
    __shared__ short H2s[32][72];
    __shared__ short H3s[32][136];
    __shared__ short WU[9216];           // WT3 as [128][72], then WT4 as [64][136]
    __shared__ short H4s[32][72];
    __shared__ float cb[842];            // b3[128] b4[64] W5[640] b5[10]
    const int tid = threadIdx.x;
    const int bm = blockIdx.x * 32;
    const int w = tid >> 6, lane = tid & 63;
    const int lr = lane & 15, lg = lane >> 4;

    for (int i = tid; i < 842; i += 256) {
        float v;
        if (i < 128) v = b3[i];
        else if (i < 192) v = b4[i - 128];
        else if (i < 832) v = W5[i - 192];
        else v = b5[i - 832];
        cb[i] = v;
    }
    #pragma unroll
    for (int p = 0; p < 4; ++p) {
        int L = tid + p * 256;           // 0..1023  (WT3 [128][64])
        int n = L >> 3;
        int kc = (L & 7) * 8;
        *reinterpret_cast<bf16x8*>(&WU[n * 72 + kc]) =
            *reinterpret_cast<const bf16x8*>(WT3 + (size_t)n * 64 + kc);
    }

    {   // gather phase: node = bm + tid/8, ci = tid%8
        const int node = bm + (tid >> 3);
        const int c8 = (tid & 7) * 8;
        float acc[8];
        bf16x8 iv = *reinterpret_cast<const bf16x8*>(C2A + (size_t)node * 128 + 64 + c8);
        #pragma unroll
        for (int i = 0; i < 8; ++i) acc[i] = bf2f(iv[i]);
        const int beg = node << 6;
        const int end = beg + min(cnt[node], CAP);
        int j = beg;
        for (; j + 3 < end; j += 4) {
            int s0 = nbr[j], s1 = nbr[j + 1], s2 = nbr[j + 2], s3 = nbr[j + 3];
            bf16x8 v0 = *reinterpret_cast<const bf16x8*>(C2A + (size_t)s0 * 128 + c8);
            bf16x8 v1 = *reinterpret_cast<const bf16x8*>(C2A + (size_t)s1 * 128 + c8);
            bf16x8 v2 = *reinterpret_cast<const bf16x8*>(C2A + (size_t)s2 * 128 + c8);
            bf16x8 v3 = *reinterpret_cast<const bf16x8*>(C2A + (size_t)s3 * 128 + c8);
            #pragma unroll
            for (int i = 0; i < 8; ++i)
                acc[i] += (bf2f(v0[i]) + bf2f(v1[i])) + (bf2f(v2[i]) + bf2f(v3[i]));
        }
        for (; j < end; ++j) {
            int s = nbr[j];
            bf16x8 vv = *reinterpret_cast<const bf16x8*>(C2A + (size_t)s * 128 + c8);
            #pragma unroll
            for (int i = 0; i < 8; ++i) acc[i] += bf2f(vv[i]);
        }
        bf16x8 o;
        #pragma unroll
        for (int i = 0; i < 8; ++i) o[i] = f2bf(acc[i]);
        *reinterpret_cast<bf16x8*>(&H2s[tid >> 3][c8]) = o;
    }
    __syncthreads();

    // mlp1: H3 = relu(H2 @ WT3^T + b3), 32x128, K=64
    {
        const int rb = (w >> 1) * 16, cbse = (w & 1) * 64;
        f32x4 a1[4] = {};
        #pragma unroll
        for (int ks = 0; ks < 2; ++ks) {
            bf16x8 a = *reinterpret_cast<const bf16x8*>(&H2s[rb + lr][ks * 32 + lg * 8]);
            #pragma unroll
            for (int nt = 0; nt < 4; ++nt) {
                bf16x8 b = *reinterpret_cast<const bf16x8*>(
                    &WU[(cbse + nt * 16 + lr) * 72 + ks * 32 + lg * 8]);
                a1[nt] = __builtin_amdgcn_mfma_f32_16x16x32_bf16(a, b, a1[nt], 0, 0, 0);
            }
        }
        #pragma unroll
        for (int r = 0; r < 4; ++r) {
            int row = rb + lg * 4 + r;
            #pragma unroll
            for (int nt = 0; nt < 4; ++nt) {
                int col = cbse + nt * 16 + lr;
                H3s[row][col] = f2bf(fmaxf(a1[nt][r] + cb[col], 0.f));
            }
        }
    }
    __syncthreads();

    #pragma unroll
    for (int p = 0; p < 4; ++p) {
        int L = tid + p * 256;           // WT4 [64][128] -> WU stride 136
        int n = L >> 4;
        int kc = (L & 15) * 8;
        *reinterpret_cast<bf16x8*>(&WU[n * 136 + kc]) =
            *reinterpret_cast<const bf16x8*>(WT4 + (size_t)n * 128 + kc);
    }
    __syncthreads();

    // mlp2: H4 = relu(H3 @ WT4^T + b4), 32x64, K=128
    {
        const int rb = (w >> 1) * 16, cbse = (w & 1) * 32;
        f32x4 a2[2] = {};
        #pragma unroll
        for (int ks = 0; ks < 4; ++ks) {
            bf16x8 a = *reinterpret_cast<const bf16x8*>(&H3s[rb + lr][ks * 32 + lg * 8]);
            #pragma unroll
            for (int nt = 0; nt < 2; ++nt) {
                bf16x8 b = *reinterpret_cast<const bf16x8*>(
                    &WU[(cbse + nt * 16 + lr) * 136 + ks * 32 + lg * 8]);
                a2[nt] = __builtin_amdgcn_mfma_f32_16x16x32_bf16(a, b, a2[nt], 0, 0, 0);
            }
        }
        #pragma unroll
        for (int r = 0; r < 4; ++r) {
            int row = rb + lg * 4 + r;
            #pragma unroll
            for (int nt = 0; nt < 2; ++nt) {
                int col = cbse + nt * 16 + lr;
                H4s[row][col] = f2bf(fmaxf(a2[nt][r] + cb[128 + col], 0.f));
            }
        }
    }
    __syncthreads();

    // head: log_softmax(H4 @ W5 + b5), threads 0..31
    if (tid < 32) {
        int node = bm + tid;
        float logit[10];
        #pragma unroll
        for (int c = 0; c < 10; ++c) logit[c] = cb[832 + c];
        #pragma unroll
        for (int k = 0; k < 64; ++k) {
            float hv = bf2f(H4s[tid][k]);
            #pragma unroll
            for (int c = 0; c < 10; ++c) logit[c] += hv * cb[192 + k * 10 + c];
        }
        float m = logit[0];
        #pragma unroll
        for (int c = 1; c < 10; ++c) m = fmaxf(m, logit[c]);
        float s = 0.f;
        #pragma unroll
        for (int c = 0; c < 10; ++c) s += expf(logit[c] - m);
        float lse = m + logf(s);
        float* o = out + (size_t)node * 10;
        #pragma unroll
        for (int c = 0; c < 10; ++c) o[c] = logit[c] - lse;
    }
}

extern "C" void kernel_launch(void* const* d_in, const int* in_sizes, int n_in,
                              void* d_out, int out_size, void* d_ws, size_t ws_size,
                              hipStream_t stream) {
    const float* x       = (const float*)d_in[0];
    const int*   edge    = (const int*)d_in[1];
    const int*   src     = edge;            // edge_index[0]
    const int*   dst     = edge + NEDGES;   // edge_index[1]
    const float* W1_rel  = (const float*)d_in[2];
    const float* W1_root = (const float*)d_in[3];
    const float* b1      = (const float*)d_in[4];
    const float* W2_rel  = (const float*)d_in[5];
    const float* W2_root = (const float*)d_in[6];
    const float* b2      = (const float*)d_in[7];
    const float* lin1_w  = (const float*)d_in[8];
    const float* lin1_b  = (const float*)d_in[9];
    const float* lin2_w  = (const float*)d_in[10];
    const float* lin2_b  = (const float*)d_in[11];
    const float* lin3_w  = (const float*)d_in[12];
    const float* lin3_b  = (const float*)d_in[13];
    float* out = (float*)d_out;

    const int M = NNODES;
    char* p = (char*)d_ws;
    auto alloc = [&](size_t bytes) { char* r = p; p += (bytes + 63) & ~63ull; return r; };
    short* WT   = (short*)alloc(98304 * 2);
    short* WT1s = WT;                 // swizzled [256][256]
    short* WT2s = WT1s + 65536;       // swizzled [128][128]
    short* WT3  = WT2s + 16384;       // [128][64] row-major
    short* WT4  = WT3 + 8192;         // [64][128] row-major
    short* XBs  = (short*)alloc((size_t)1252 * 4096 * 2);  // x bf16, chunk layout (padded)
    short* C1A  = (short*)alloc((size_t)M * 256 * 2);      // row-major
    short* C2A  = (short*)alloc((size_t)M * 128 * 2);      // row-major
    int* cnt = (int*)alloc(NNODES * 4);
    int* nbr = (int*)alloc((size_t)NNODES * CAP * 4);      // buckets

    hipMemsetAsync(cnt, 0, NNODES * sizeof(int), stream);
    prep_kernel<<<384 + 2500 + NEDGES / 256, 256, 0, stream>>>(
        W1_rel, W1_root, W2_rel, W2_root, lin1_w, lin2_w, WT, x, XBs,
        src, dst, cnt, nbr);

    gemm1_swz<<<4 * 313, 256, 0, stream>>>(XBs, WT1s, b1, C1A, M);
    gather1_gemm2<<<NNODES / 16, 256, 0, stream>>>(C1A, cnt, nbr, WT2s, b2, C2A);
    gather2_mlp<<<NNODES / 32, 256, 0, stream>>>(C2A, cnt, nbr, WT3, lin1_b,
                                                 WT4, lin2_b, lin3_w, lin3_b, out);
}